// Round 1
// baseline (429.386 us; speedup 1.0000x reference)
//
#include <hip/hip_runtime.h>
#include <hip/hip_bf16.h>

#define VOCAB 100000
#define DIM   512
#define BATCH 4096
#define SEQ   200
#define HID   256
#define OUTN  20

typedef __attribute__((ext_vector_type(8))) short short8;
typedef __attribute__((ext_vector_type(4))) float floatx4;

static __device__ __forceinline__ unsigned short f2bf(float f) {
    __hip_bfloat16 b = __float2bfloat16(f);
    return *(unsigned short*)&b;
}
static __device__ __forceinline__ float bf2f(unsigned short u) {
    unsigned int v = (unsigned int)u << 16;
    return *(float*)&v;
}

// ---------------------------------------------------------------------------
// Kernel 0: emb_table fp32 [VOCAB, 512] -> bf16 [VOCAB, 512]. Pure stream.
// NT loads on the fp32 source; normal stores so the bf16 table stays
// cache-resident for the gather.
// ---------------------------------------------------------------------------
__global__ __launch_bounds__(256) void k_cvt(
    const float* __restrict__ src, unsigned short* __restrict__ dst)
{
    const int n8 = VOCAB * DIM / 8;          // 6.4M groups of 8
    int i = blockIdx.x * 256 + threadIdx.x;
    const int stride = gridDim.x * 256;
    const floatx4* s4 = (const floatx4*)src;
    short8* d8 = (short8*)dst;
    for (; i < n8; i += stride) {
        const floatx4 a = __builtin_nontemporal_load(&s4[2 * i]);
        const floatx4 b = __builtin_nontemporal_load(&s4[2 * i + 1]);
        short8 o;
        o[0] = (short)f2bf(a[0]); o[1] = (short)f2bf(a[1]);
        o[2] = (short)f2bf(a[2]); o[3] = (short)f2bf(a[3]);
        o[4] = (short)f2bf(b[0]); o[5] = (short)f2bf(b[1]);
        o[6] = (short)f2bf(b[2]); o[7] = (short)f2bf(b[3]);
        d8[i] = o;
    }
}

// ---------------------------------------------------------------------------
// Kernel 1: gather+reduce over bf16 table. 512 threads = 8 waves per batch
// row (was 4): 2x the waves-in-flight to push the random-fetch path harder.
// Each wave reads full 1KB rows (64 lanes x 16B) for its 25 tokens.
// sidx holds PRE-MULTIPLIED byte offsets (kills the per-iter 64-bit mul).
// ---------------------------------------------------------------------------
__global__ __launch_bounds__(512) void k_reduce_bf(
    const unsigned short* __restrict__ embb, const int* __restrict__ x,
    const int* __restrict__ lengths, unsigned short* __restrict__ repb)
{
    const int b = blockIdx.x;
    const int t = threadIdx.x;
    const int w = t >> 6;            // wave 0..7
    const int lane = t & 63;

    __shared__ int sidx[SEQ];        // byte offsets into bf16 table
    if (t < SEQ) sidx[t] = x[b * SEQ + t] * (DIM * 2);
    __syncthreads();

    float s[8] = {0.f, 0.f, 0.f, 0.f, 0.f, 0.f, 0.f, 0.f};
    float m[8] = {-1e30f, -1e30f, -1e30f, -1e30f, -1e30f, -1e30f, -1e30f, -1e30f};

    const char* base = (const char*)embb + lane * 16;   // lane's 8 columns
    const int i0 = w * (SEQ / 8);                       // 25 tokens per wave

#pragma unroll 5
    for (int i = i0; i < i0 + SEQ / 8; ++i) {
        const short8 v = *(const short8*)(base + sidx[i]);
#pragma unroll
        for (int j = 0; j < 8; ++j) {
            const float f = bf2f((unsigned short)v[j]);
            s[j] += f;
            m[j] = fmaxf(m[j], f);
        }
    }

    __shared__ float red[8][2][DIM];   // [wave][sum|max][col] = 32 KB
    *(float4*)&red[w][0][lane * 8]     = make_float4(s[0], s[1], s[2], s[3]);
    *(float4*)&red[w][0][lane * 8 + 4] = make_float4(s[4], s[5], s[6], s[7]);
    *(float4*)&red[w][1][lane * 8]     = make_float4(m[0], m[1], m[2], m[3]);
    *(float4*)&red[w][1][lane * 8 + 4] = make_float4(m[4], m[5], m[6], m[7]);
    __syncthreads();

    // 512 threads x 1 column each
    const float inv = 1.0f / (float)lengths[b];
    const int c = t;                 // 0..511
    float sv = red[0][0][c];
    float mv = red[0][1][c];
#pragma unroll
    for (int ww = 1; ww < 8; ++ww) {
        sv += red[ww][0][c];
        mv = fmaxf(mv, red[ww][1][c]);
    }
    unsigned short* row = repb + (size_t)b * (2 * DIM);
    row[c]       = f2bf(sv * inv);   // cols [0,512)
    row[DIM + c] = f2bf(mv);         // cols [512,1024)
}

// ---------------------------------------------------------------------------
// Kernel 1 (fallback path, fp32 table): gather direct.
// ---------------------------------------------------------------------------
__global__ __launch_bounds__(128) void k_reduce(
    const float* __restrict__ emb, const int* __restrict__ x,
    const int* __restrict__ lengths, unsigned short* __restrict__ repb)
{
    const int b = blockIdx.x;
    const int t = threadIdx.x;

    __shared__ int sidx[SEQ];
    for (int i = t; i < SEQ; i += 128) sidx[i] = x[b * SEQ + i];
    __syncthreads();

    const float4* embv = (const float4*)emb;
    float4 s = make_float4(0.f, 0.f, 0.f, 0.f);
    float4 m = make_float4(-1e30f, -1e30f, -1e30f, -1e30f);

#pragma unroll 4
    for (int i = 0; i < SEQ; ++i) {
        const float4 v = embv[(size_t)sidx[i] * (DIM / 4) + t];
        s.x += v.x; s.y += v.y; s.z += v.z; s.w += v.w;
        m.x = fmaxf(m.x, v.x); m.y = fmaxf(m.y, v.y);
        m.z = fmaxf(m.z, v.z); m.w = fmaxf(m.w, v.w);
    }

    const float inv = 1.0f / (float)lengths[b];
    unsigned long long mu =
          (unsigned long long)f2bf(s.x * inv)
        | ((unsigned long long)f2bf(s.y * inv) << 16)
        | ((unsigned long long)f2bf(s.z * inv) << 32)
        | ((unsigned long long)f2bf(s.w * inv) << 48);
    unsigned long long xu =
          (unsigned long long)f2bf(m.x)
        | ((unsigned long long)f2bf(m.y) << 16)
        | ((unsigned long long)f2bf(m.z) << 32)
        | ((unsigned long long)f2bf(m.w) << 48);

    unsigned short* row = repb + (size_t)b * (2 * DIM);
    *(unsigned long long*)(row + 4 * t)       = mu;
    *(unsigned long long*)(row + DIM + 4 * t) = xu;
}

// ---------------------------------------------------------------------------
// Kernel 1b: W1 [1024, 256] fp32 -> W1T [256, 1024] bf16 (transpose+convert).
// ---------------------------------------------------------------------------
__global__ __launch_bounds__(256) void k_w1t(
    const float* __restrict__ W1, unsigned short* __restrict__ W1T)
{
    __shared__ unsigned short s[64][65];
    const int n0 = blockIdx.x * 64;
    const int k0 = blockIdx.y * 64;
    const int t = threadIdx.x;

#pragma unroll
    for (int i = 0; i < 4; ++i) {
        const int kk = (t >> 4) + i * 16;
        const int cc = (t & 15) * 4;
        const float4 v = *(const float4*)&W1[(size_t)(k0 + kk) * HID + n0 + cc];
        s[cc + 0][kk] = f2bf(v.x);
        s[cc + 1][kk] = f2bf(v.y);
        s[cc + 2][kk] = f2bf(v.z);
        s[cc + 3][kk] = f2bf(v.w);
    }
    __syncthreads();

#pragma unroll
    for (int i = 0; i < 4; ++i) {
        const int nn = (t >> 4) + i * 16;
        const int kq = (t & 15) * 4;
        unsigned long long u =
              (unsigned long long)s[nn][kq + 0]
            | ((unsigned long long)s[nn][kq + 1] << 16)
            | ((unsigned long long)s[nn][kq + 2] << 32)
            | ((unsigned long long)s[nn][kq + 3] << 48);
        *(unsigned long long*)&W1T[(size_t)(n0 + nn) * (2 * DIM) + k0 + kq] = u;
    }
}

// ---------------------------------------------------------------------------
// Kernel 2 (FUSED): logits = relu(rep @ W1 + b1) @ W2 + b2.
// One block = 32 rows x all 256 cols. BK=64 (16 K-iters, 2 barriers each).
// 4 waves; wave wv owns cols [wv*64, wv*64+64). After the MFMA loop the
// relu'd h-tile goes to LDS and the tiny 20-col GEMM runs from LDS,
// writing logits directly. No h round-trip through HBM, one fewer launch.
// ---------------------------------------------------------------------------
#define BM3 32
#define BK3 64
#define SPAD 72   // 64 + 8 shorts: frag-read lane stride 144B (2-way, free)
#define HP4 260   // 256 + 4 pad floats

__global__ __launch_bounds__(256) void k_fused(
    const unsigned short* __restrict__ repb,
    const unsigned short* __restrict__ w1t,
    const float* __restrict__ b1,
    const float* __restrict__ W2,
    const float* __restrict__ b2,
    float* __restrict__ outp)
{
    // union: staging (sA 4.6KB + sB 36.9KB) vs epilogue (sh 33.3KB + swt 20.8KB)
    __shared__ __align__(16) char smem[54080];
    unsigned short (*sA)[SPAD] = (unsigned short(*)[SPAD])smem;                 // [32][72]
    unsigned short (*sB)[SPAD] = (unsigned short(*)[SPAD])(smem + BM3 * SPAD * 2); // [256][72]
    float (*sh)[HP4]  = (float(*)[HP4])smem;                                    // [32][260]
    float (*swt)[HP4] = (float(*)[HP4])(smem + BM3 * HP4 * 4);                  // [20][260]
    __shared__ float sb2[OUTN];

    const int K = 2 * DIM;               // 1024
    const int rowBase = blockIdx.x * BM3;
    const int t = threadIdx.x;
    const int lane = t & 63;
    const int wv = t >> 6;               // wave 0..3 -> col block
    const int lm = lane & 15;
    const int lq = lane >> 4;

    // staging assignment: A: thread t -> row t>>3, k-chunk t&7 (1 short8)
    //                     B: thread t -> col t, 8 k-chunks (8 short8)
    const int ar = t >> 3;
    const int ac = t & 7;
    const unsigned short* gA = repb + (size_t)(rowBase + ar) * K + ac * 8;
    const unsigned short* gB = w1t + (size_t)t * K;

    floatx4 acc[2][4];
#pragma unroll
    for (int i = 0; i < 2; ++i)
#pragma unroll
        for (int j = 0; j < 4; ++j)
            acc[i][j] = (floatx4){0.f, 0.f, 0.f, 0.f};

    short8 pa = *(const short8*)gA;
    short8 pb[8];
#pragma unroll
    for (int cth = 0; cth < 8; ++cth) pb[cth] = *(const short8*)(gB + cth * 8);

    for (int k0 = 0; k0 < K; k0 += BK3) {
        __syncthreads();
        *(short8*)&sA[ar][ac * 8] = pa;
#pragma unroll
        for (int cth = 0; cth < 8; ++cth) *(short8*)&sB[t][cth * 8] = pb[cth];
        __syncthreads();

        if (k0 + BK3 < K) {
            pa = *(const short8*)(gA + k0 + BK3);
#pragma unroll
            for (int cth = 0; cth < 8; ++cth)
                pb[cth] = *(const short8*)(gB + k0 + BK3 + cth * 8);
        }

#pragma unroll
        for (int ks = 0; ks < 2; ++ks) {
            const short8 a0 = *(const short8*)&sA[lm][ks * 32 + lq * 8];
            const short8 a1 = *(const short8*)&sA[16 + lm][ks * 32 + lq * 8];
#pragma unroll
            for (int nt = 0; nt < 4; ++nt) {
                const short8 bfr = *(const short8*)&sB[wv * 64 + nt * 16 + lm][ks * 32 + lq * 8];
                acc[0][nt] = __builtin_amdgcn_mfma_f32_16x16x32_bf16(a0, bfr, acc[0][nt], 0, 0, 0);
                acc[1][nt] = __builtin_amdgcn_mfma_f32_16x16x32_bf16(a1, bfr, acc[1][nt], 0, 0, 0);
            }
        }
    }

    __syncthreads();   // done reading sA/sB; smem is reused below

    // h tile (bias + relu) -> LDS
#pragma unroll
    for (int nt = 0; nt < 4; ++nt) {
        const int col = wv * 64 + nt * 16 + lm;
        const float bb = b1[col];
#pragma unroll
        for (int mt = 0; mt < 2; ++mt) {
#pragma unroll
            for (int rg = 0; rg < 4; ++rg) {
                const int row = mt * 16 + lq * 4 + rg;
                sh[row][col] = fmaxf(acc[mt][nt][rg] + bb, 0.f);
            }
        }
    }
    // stage W2^T [20][256] and b2
    {
        const int k = t;  // 0..255
#pragma unroll
        for (int cc = 0; cc < OUTN; ++cc) swt[cc][k] = W2[k * OUTN + cc];
    }
    if (t < OUTN) sb2[t] = b2[t];
    __syncthreads();

    // second GEMM: thread t -> row t>>3 (0..31), col-slot t&7 covering
    // cols {cs, cs+8, cs+16(<20)}
    const int r  = t >> 3;
    const int cs = t & 7;
    float acc0 = 0.f, acc1 = 0.f, acc2 = 0.f;
#pragma unroll 8
    for (int k = 0; k < HID; k += 4) {
        const float4 a  = *(const float4*)&sh[r][k];
        const float4 w0 = *(const float4*)&swt[cs][k];
        const float4 w1v = *(const float4*)&swt[cs + 8][k];
        acc0 += a.x * w0.x + a.y * w0.y + a.z * w0.z + a.w * w0.w;
        acc1 += a.x * w1v.x + a.y * w1v.y + a.z * w1v.z + a.w * w1v.w;
        if (cs + 16 < OUTN) {
            const float4 w2v = *(const float4*)&swt[cs + 16][k];
            acc2 += a.x * w2v.x + a.y * w2v.y + a.z * w2v.z + a.w * w2v.w;
        }
    }
    float* orow = outp + (size_t)(rowBase + r) * OUTN;
    orow[cs]     = acc0 + sb2[cs];
    orow[cs + 8] = acc1 + sb2[cs + 8];
    if (cs + 16 < OUTN) orow[cs + 16] = acc2 + sb2[cs + 16];
}

// ---------------------------------------------------------------------------
// Fallback GEMMs (fp32-table path only)
// ---------------------------------------------------------------------------
#define APAD 40

__global__ __launch_bounds__(256) void k_gemm1(
    const unsigned short* __restrict__ repb,
    const unsigned short* __restrict__ w1t,
    const float* __restrict__ bias, float* __restrict__ h)
{
    const int K = 2 * DIM;
    const int rowBase = blockIdx.y * 64;
    const int colBase = blockIdx.x * 64;
    const int tid  = threadIdx.x;
    const int lane = tid & 63;
    const int wv   = tid >> 6;
    const int wm   = wv & 1;
    const int wn   = wv >> 1;

    __shared__ unsigned short sA[64][APAD];
    __shared__ unsigned short sB[64][APAD];

    const int r  = tid >> 2;
    const int kq = tid & 3;

    const unsigned short* gA = repb + (size_t)(rowBase + r) * K + kq * 8;
    const unsigned short* gB = w1t  + (size_t)(colBase + r) * K + kq * 8;

    floatx4 acc[2][2] = {{{0.f,0.f,0.f,0.f},{0.f,0.f,0.f,0.f}},
                         {{0.f,0.f,0.f,0.f},{0.f,0.f,0.f,0.f}}};

    short8 pa = *(const short8*)gA;
    short8 pb = *(const short8*)gB;

    const int lm = lane & 15;
    const int lq = lane >> 4;
    for (int k0 = 0; k0 < K; k0 += 32) {
        __syncthreads();
        *(short8*)&sA[r][kq * 8] = pa;
        *(short8*)&sB[r][kq * 8] = pb;
        __syncthreads();

        if (k0 + 32 < K) {
            pa = *(const short8*)(gA + k0 + 32);
            pb = *(const short8*)(gB + k0 + 32);
        }

        const short8 a0 = *(const short8*)&sA[wm * 32 + lm][lq * 8];
        const short8 a1 = *(const short8*)&sA[wm * 32 + 16 + lm][lq * 8];
        const short8 b0 = *(const short8*)&sB[wn * 32 + lm][lq * 8];
        const short8 b1 = *(const short8*)&sB[wn * 32 + 16 + lm][lq * 8];

        acc[0][0] = __builtin_amdgcn_mfma_f32_16x16x32_bf16(a0, b0, acc[0][0], 0, 0, 0);
        acc[0][1] = __builtin_amdgcn_mfma_f32_16x16x32_bf16(a0, b1, acc[0][1], 0, 0, 0);
        acc[1][0] = __builtin_amdgcn_mfma_f32_16x16x32_bf16(a1, b0, acc[1][0], 0, 0, 0);
        acc[1][1] = __builtin_amdgcn_mfma_f32_16x16x32_bf16(a1, b1, acc[1][1], 0, 0, 0);
    }

#pragma unroll
    for (int nt = 0; nt < 2; ++nt) {
        const int col = colBase + wn * 32 + nt * 16 + lm;
        const float bb = bias[col];
#pragma unroll
        for (int mt = 0; mt < 2; ++mt) {
#pragma unroll
            for (int rg = 0; rg < 4; ++rg) {
                const int row = rowBase + wm * 32 + mt * 16 + lq * 4 + rg;
                h[(size_t)row * HID + col] = fmaxf(acc[mt][nt][rg] + bb, 0.f);
            }
        }
    }
}

#define R3 32

__global__ __launch_bounds__(256) void k_gemm2(
    const float* __restrict__ H, const float* __restrict__ W2,
    const float* __restrict__ b2, float* __restrict__ outp)
{
    __shared__ float sh[R3][HP4];
    __shared__ float swt[OUTN][HP4];
    __shared__ float sb[OUTN];

    const int t = threadIdx.x;
    const int rowBase = blockIdx.x * R3;

    const float4* H4 = (const float4*)H;
    for (int i = t; i < R3 * (HID / 4); i += 256) {
        const int r  = i >> 6;
        const int c4 = i & 63;
        *(float4*)&sh[r][c4 * 4] = H4[(size_t)(rowBase + r) * (HID / 4) + c4];
    }
    {
        const int k = t;
#pragma unroll
        for (int c = 0; c < OUTN; ++c) swt[c][k] = W2[k * OUTN + c];
    }
    if (t < OUTN) sb[t] = b2[t];
    __syncthreads();

    const int r  = t & 31;
    const int cs = t >> 5;
    float a0 = sb[cs], a1 = sb[cs + 8], a2 = (cs + 16 < OUTN) ? sb[cs + 16] : 0.f;
    float acc0 = 0.f, acc1 = 0.f, acc2 = 0.f;

#pragma unroll 8
    for (int k = 0; k < HID; k += 4) {
        const float4 a = *(const float4*)&sh[r][k];
        const float4 w0 = *(const float4*)&swt[cs][k];
        const float4 w1 = *(const float4*)&swt[cs + 8][k];
        acc0 += a.x * w0.x + a.y * w0.y + a.z * w0.z + a.w * w0.w;
        acc1 += a.x * w1.x + a.y * w1.y + a.z * w1.z + a.w * w1.w;
        if (cs + 16 < OUTN) {
            const float4 w2 = *(const float4*)&swt[cs + 16][k];
            acc2 += a.x * w2.x + a.y * w2.y + a.z * w2.z + a.w * w2.w;
        }
    }

    float* orow = outp + (size_t)(rowBase + r) * OUTN;
    orow[cs]     = acc0 + a0;
    orow[cs + 8] = acc1 + a1;
    if (cs + 16 < OUTN) orow[cs + 16] = acc2 + a2;
}

// ---------------------------------------------------------------------------
extern "C" void kernel_launch(void* const* d_in, const int* in_sizes, int n_in,
                              void* d_out, int out_size, void* d_ws, size_t ws_size,
                              hipStream_t stream)
{
    const float* emb     = (const float*)d_in[0];
    const float* W1      = (const float*)d_in[1];
    const float* b1      = (const float*)d_in[2];
    const float* W2      = (const float*)d_in[3];
    const float* b2      = (const float*)d_in[4];
    const int*   x       = (const int*)d_in[5];
    const int*   lengths = (const int*)d_in[6];

    float* out = (float*)d_out;

    const size_t embbN = (size_t)VOCAB * DIM;            // bf16 elems, 102.4 MB
    const size_t repbN = (size_t)BATCH * 2 * DIM;        // bf16 elems,   8.4 MB
    const size_t w1tN  = (size_t)HID * 2 * DIM;          // bf16 elems,   0.5 MB
    const size_t hN    = (size_t)BATCH * HID;            // fp32 elems (fallback)
    const size_t needFast = (embbN + repbN + w1tN) * 2 + 256;

    if (ws_size >= needFast) {
        unsigned short* embb = (unsigned short*)d_ws;
        unsigned short* repb = embb + embbN;
        unsigned short* w1t  = repb + repbN;

        k_cvt<<<2048, 256, 0, stream>>>(emb, embb);
        k_w1t<<<dim3(HID / 64, (2 * DIM) / 64), 256, 0, stream>>>(W1, w1t);
        k_reduce_bf<<<BATCH, 512, 0, stream>>>(embb, x, lengths, repb);
        k_fused<<<BATCH / BM3, 256, 0, stream>>>(repb, w1t, b1, W2, b2, out);
    } else {
        unsigned short* repb = (unsigned short*)d_ws;
        unsigned short* w1t  = repb + repbN;
        float* h = (float*)(w1t + w1tN);

        k_w1t<<<dim3(HID / 64, (2 * DIM) / 64), 256, 0, stream>>>(W1, w1t);
        k_reduce<<<BATCH, 128, 0, stream>>>(emb, x, lengths, repb);
        k_gemm1<<<dim3(HID / 64, BATCH / 64), 256, 0, stream>>>(repb, w1t, b1, h);
        k_gemm2<<<BATCH / R3, 256, 0, stream>>>(h, W2, b2, out);
    }
}

// Round 3
// 419.194 us; speedup vs baseline: 1.0243x; 1.0243x over previous
//
#include <hip/hip_runtime.h>
#include <hip/hip_bf16.h>

#define VOCAB 100000
#define DIM   512
#define BATCH 4096
#define SEQ   200
#define HID   256
#define OUTN  20

typedef __attribute__((ext_vector_type(8))) short short8;
typedef __attribute__((ext_vector_type(4))) float floatx4;

static __device__ __forceinline__ unsigned short f2bf(float f) {
    __hip_bfloat16 b = __float2bfloat16(f);
    return *(unsigned short*)&b;
}
static __device__ __forceinline__ float bf2f(unsigned short u) {
    unsigned int v = (unsigned int)u << 16;
    return *(float*)&v;
}

// ---------------------------------------------------------------------------
// Kernel 0: emb_table fp32 [VOCAB, 512] -> bf16 [VOCAB, 512]. Pure stream.
// NT loads on the fp32 source (never re-read); normal stores so the bf16
// table stays cache-resident for the gather. At copy roofline (~80 us).
// ---------------------------------------------------------------------------
__global__ __launch_bounds__(256) void k_cvt(
    const float* __restrict__ src, unsigned short* __restrict__ dst)
{
    const int n8 = VOCAB * DIM / 8;          // 6.4M groups of 8
    int i = blockIdx.x * 256 + threadIdx.x;
    const int stride = gridDim.x * 256;
    const floatx4* s4 = (const floatx4*)src;
    short8* d8 = (short8*)dst;
    for (; i < n8; i += stride) {
        const floatx4 a = __builtin_nontemporal_load(&s4[2 * i]);
        const floatx4 b = __builtin_nontemporal_load(&s4[2 * i + 1]);
        short8 o;
        o[0] = (short)f2bf(a[0]); o[1] = (short)f2bf(a[1]);
        o[2] = (short)f2bf(a[2]); o[3] = (short)f2bf(a[3]);
        o[4] = (short)f2bf(b[0]); o[5] = (short)f2bf(b[1]);
        o[6] = (short)f2bf(b[2]); o[7] = (short)f2bf(b[3]);
        d8[i] = o;
    }
}

// ---------------------------------------------------------------------------
// Kernel 1: gather+reduce over bf16 table. 512 threads = 8 waves per batch
// row; each wave reads full 1KB rows (64 lanes x 16B) for its 25 tokens.
// sidx holds PRE-MULTIPLIED byte offsets. Bandwidth-bound on the L2-miss
// path (~7.1 TB/s effective logical) — near its floor.
// ---------------------------------------------------------------------------
__global__ __launch_bounds__(512) void k_reduce_bf(
    const unsigned short* __restrict__ embb, const int* __restrict__ x,
    const int* __restrict__ lengths, unsigned short* __restrict__ repb)
{
    const int b = blockIdx.x;
    const int t = threadIdx.x;
    const int w = t >> 6;            // wave 0..7
    const int lane = t & 63;

    __shared__ int sidx[SEQ];        // byte offsets into bf16 table
    if (t < SEQ) sidx[t] = x[b * SEQ + t] * (DIM * 2);
    __syncthreads();

    float s[8] = {0.f, 0.f, 0.f, 0.f, 0.f, 0.f, 0.f, 0.f};
    float m[8] = {-1e30f, -1e30f, -1e30f, -1e30f, -1e30f, -1e30f, -1e30f, -1e30f};

    const char* base = (const char*)embb + lane * 16;   // lane's 8 columns
    const int i0 = w * (SEQ / 8);                       // 25 tokens per wave

#pragma unroll 5
    for (int i = i0; i < i0 + SEQ / 8; ++i) {
        const short8 v = *(const short8*)(base + sidx[i]);
#pragma unroll
        for (int j = 0; j < 8; ++j) {
            const float f = bf2f((unsigned short)v[j]);
            s[j] += f;
            m[j] = fmaxf(m[j], f);
        }
    }

    __shared__ float red[8][2][DIM];   // [wave][sum|max][col] = 32 KB
    *(float4*)&red[w][0][lane * 8]     = make_float4(s[0], s[1], s[2], s[3]);
    *(float4*)&red[w][0][lane * 8 + 4] = make_float4(s[4], s[5], s[6], s[7]);
    *(float4*)&red[w][1][lane * 8]     = make_float4(m[0], m[1], m[2], m[3]);
    *(float4*)&red[w][1][lane * 8 + 4] = make_float4(m[4], m[5], m[6], m[7]);
    __syncthreads();

    // 512 threads x 1 column each
    const float inv = 1.0f / (float)lengths[b];
    const int c = t;                 // 0..511
    float sv = red[0][0][c];
    float mv = red[0][1][c];
#pragma unroll
    for (int ww = 1; ww < 8; ++ww) {
        sv += red[ww][0][c];
        mv = fmaxf(mv, red[ww][1][c]);
    }
    unsigned short* row = repb + (size_t)b * (2 * DIM);
    row[c]       = f2bf(sv * inv);   // cols [0,512)
    row[DIM + c] = f2bf(mv);         // cols [512,1024)
}

// ---------------------------------------------------------------------------
// Kernel 1 (fallback path, fp32 table): gather direct.
// ---------------------------------------------------------------------------
__global__ __launch_bounds__(128) void k_reduce(
    const float* __restrict__ emb, const int* __restrict__ x,
    const int* __restrict__ lengths, unsigned short* __restrict__ repb)
{
    const int b = blockIdx.x;
    const int t = threadIdx.x;

    __shared__ int sidx[SEQ];
    for (int i = t; i < SEQ; i += 128) sidx[i] = x[b * SEQ + i];
    __syncthreads();

    const float4* embv = (const float4*)emb;
    float4 s = make_float4(0.f, 0.f, 0.f, 0.f);
    float4 m = make_float4(-1e30f, -1e30f, -1e30f, -1e30f);

#pragma unroll 4
    for (int i = 0; i < SEQ; ++i) {
        const float4 v = embv[(size_t)sidx[i] * (DIM / 4) + t];
        s.x += v.x; s.y += v.y; s.z += v.z; s.w += v.w;
        m.x = fmaxf(m.x, v.x); m.y = fmaxf(m.y, v.y);
        m.z = fmaxf(m.z, v.z); m.w = fmaxf(m.w, v.w);
    }

    const float inv = 1.0f / (float)lengths[b];
    unsigned long long mu =
          (unsigned long long)f2bf(s.x * inv)
        | ((unsigned long long)f2bf(s.y * inv) << 16)
        | ((unsigned long long)f2bf(s.z * inv) << 32)
        | ((unsigned long long)f2bf(s.w * inv) << 48);
    unsigned long long xu =
          (unsigned long long)f2bf(m.x)
        | ((unsigned long long)f2bf(m.y) << 16)
        | ((unsigned long long)f2bf(m.z) << 32)
        | ((unsigned long long)f2bf(m.w) << 48);

    unsigned short* row = repb + (size_t)b * (2 * DIM);
    *(unsigned long long*)(row + 4 * t)       = mu;
    *(unsigned long long*)(row + DIM + 4 * t) = xu;
}

// ---------------------------------------------------------------------------
// Kernel 1b: W1 [1024, 256] fp32 -> W1T [256, 1024] bf16 (transpose+convert).
// ---------------------------------------------------------------------------
__global__ __launch_bounds__(256) void k_w1t(
    const float* __restrict__ W1, unsigned short* __restrict__ W1T)
{
    __shared__ unsigned short s[64][65];
    const int n0 = blockIdx.x * 64;
    const int k0 = blockIdx.y * 64;
    const int t = threadIdx.x;

#pragma unroll
    for (int i = 0; i < 4; ++i) {
        const int kk = (t >> 4) + i * 16;
        const int cc = (t & 15) * 4;
        const float4 v = *(const float4*)&W1[(size_t)(k0 + kk) * HID + n0 + cc];
        s[cc + 0][kk] = f2bf(v.x);
        s[cc + 1][kk] = f2bf(v.y);
        s[cc + 2][kk] = f2bf(v.z);
        s[cc + 3][kk] = f2bf(v.w);
    }
    __syncthreads();

#pragma unroll
    for (int i = 0; i < 4; ++i) {
        const int nn = (t >> 4) + i * 16;
        const int kq = (t & 15) * 4;
        unsigned long long u =
              (unsigned long long)s[nn][kq + 0]
            | ((unsigned long long)s[nn][kq + 1] << 16)
            | ((unsigned long long)s[nn][kq + 2] << 32)
            | ((unsigned long long)s[nn][kq + 3] << 48);
        *(unsigned long long*)&W1T[(size_t)(n0 + nn) * (2 * DIM) + k0 + kq] = u;
    }
}

// ---------------------------------------------------------------------------
// Kernel 2: h = relu(rep @ W1 + b1) via bf16 MFMA 16x16x32, fp32 accum.
// 256 blocks (full GPU), BK=64: 16 K-iters, 32 barriers (was 64 at BK=32).
// Per wave per iter: 2 k-slices x 4 MFMA.
// ---------------------------------------------------------------------------
#define APAD 72   // 64 + 8 shorts: frag-read lane stride 144B -> 2-way (free)

__global__ __launch_bounds__(256) void k_gemm1(
    const unsigned short* __restrict__ repb,
    const unsigned short* __restrict__ w1t,
    const float* __restrict__ bias, float* __restrict__ h)
{
    const int K = 2 * DIM;               // 1024
    const int rowBase = blockIdx.y * 64; // M
    const int colBase = blockIdx.x * 64; // N
    const int tid  = threadIdx.x;
    const int lane = tid & 63;
    const int wv   = tid >> 6;
    const int wm   = wv & 1;
    const int wn   = wv >> 1;

    __shared__ unsigned short sA[64][APAD];   // 9.2 KB
    __shared__ unsigned short sB[64][APAD];   // 9.2 KB

    const int r  = tid >> 2;   // 0..63
    const int kq = tid & 3;    // chunk: kq*8 and 32+kq*8

    const unsigned short* gA = repb + (size_t)(rowBase + r) * K + kq * 8;
    const unsigned short* gB = w1t  + (size_t)(colBase + r) * K + kq * 8;

    floatx4 acc[2][2] = {{{0.f,0.f,0.f,0.f},{0.f,0.f,0.f,0.f}},
                         {{0.f,0.f,0.f,0.f},{0.f,0.f,0.f,0.f}}};

    short8 pa0 = *(const short8*)gA;
    short8 pa1 = *(const short8*)(gA + 32);
    short8 pb0 = *(const short8*)gB;
    short8 pb1 = *(const short8*)(gB + 32);

    const int lm = lane & 15;
    const int lq = lane >> 4;
    for (int k0 = 0; k0 < K; k0 += 64) {
        __syncthreads();
        *(short8*)&sA[r][kq * 8]      = pa0;
        *(short8*)&sA[r][32 + kq * 8] = pa1;
        *(short8*)&sB[r][kq * 8]      = pb0;
        *(short8*)&sB[r][32 + kq * 8] = pb1;
        __syncthreads();

        if (k0 + 64 < K) {
            pa0 = *(const short8*)(gA + k0 + 64);
            pa1 = *(const short8*)(gA + k0 + 96);
            pb0 = *(const short8*)(gB + k0 + 64);
            pb1 = *(const short8*)(gB + k0 + 96);
        }

#pragma unroll
        for (int ks = 0; ks < 2; ++ks) {
            const short8 a0 = *(const short8*)&sA[wm * 32 + lm][ks * 32 + lq * 8];
            const short8 a1 = *(const short8*)&sA[wm * 32 + 16 + lm][ks * 32 + lq * 8];
            const short8 b0 = *(const short8*)&sB[wn * 32 + lm][ks * 32 + lq * 8];
            const short8 b1 = *(const short8*)&sB[wn * 32 + 16 + lm][ks * 32 + lq * 8];

            acc[0][0] = __builtin_amdgcn_mfma_f32_16x16x32_bf16(a0, b0, acc[0][0], 0, 0, 0);
            acc[0][1] = __builtin_amdgcn_mfma_f32_16x16x32_bf16(a0, b1, acc[0][1], 0, 0, 0);
            acc[1][0] = __builtin_amdgcn_mfma_f32_16x16x32_bf16(a1, b0, acc[1][0], 0, 0, 0);
            acc[1][1] = __builtin_amdgcn_mfma_f32_16x16x32_bf16(a1, b1, acc[1][1], 0, 0, 0);
        }
    }

#pragma unroll
    for (int nt = 0; nt < 2; ++nt) {
        const int col = colBase + wn * 32 + nt * 16 + lm;
        const float bb = bias[col];
#pragma unroll
        for (int mt = 0; mt < 2; ++mt) {
#pragma unroll
            for (int rg = 0; rg < 4; ++rg) {
                const int row = rowBase + wm * 32 + mt * 16 + lq * 4 + rg;
                h[(size_t)row * HID + col] = fmaxf(acc[mt][nt][rg] + bb, 0.f);
            }
        }
    }
}

// ---------------------------------------------------------------------------
// Kernel 3: logits = h @ W2 + b2.  h fp32 [4096,256], W2 [256,20].
// Transposed W2 in LDS; float4 k-loop. Thread t -> row r = t&31,
// col-slot cs = t>>5 (0..7) covering cols {cs, cs+8, cs+16(<20)}.
// ---------------------------------------------------------------------------
#define R3 32
#define HP4 260   // 256 + 4 pad

__global__ __launch_bounds__(256) void k_gemm2(
    const float* __restrict__ H, const float* __restrict__ W2,
    const float* __restrict__ b2, float* __restrict__ outp)
{
    __shared__ float sh[R3][HP4];      // 33.3 KB
    __shared__ float swt[OUTN][HP4];   // 20.8 KB
    __shared__ float sb[OUTN];

    const int t = threadIdx.x;
    const int rowBase = blockIdx.x * R3;

    const float4* H4 = (const float4*)H;
    for (int i = t; i < R3 * (HID / 4); i += 256) {
        const int r  = i >> 6;
        const int c4 = i & 63;
        *(float4*)&sh[r][c4 * 4] = H4[(size_t)(rowBase + r) * (HID / 4) + c4];
    }
    // W2 [256][20] -> swt[20][256]; thread t = k row
    {
        const int k = t;  // 0..255
#pragma unroll
        for (int c = 0; c < OUTN; ++c) swt[c][k] = W2[k * OUTN + c];
    }
    if (t < OUTN) sb[t] = b2[t];
    __syncthreads();

    const int r  = t & 31;
    const int cs = t >> 5;          // 0..7
    float a0 = sb[cs], a1 = sb[cs + 8], a2 = (cs + 16 < OUTN) ? sb[cs + 16] : 0.f;
    float acc0 = 0.f, acc1 = 0.f, acc2 = 0.f;

#pragma unroll 8
    for (int k = 0; k < HID; k += 4) {
        const float4 a = *(const float4*)&sh[r][k];
        const float4 w0 = *(const float4*)&swt[cs][k];
        const float4 w1 = *(const float4*)&swt[cs + 8][k];
        acc0 += a.x * w0.x + a.y * w0.y + a.z * w0.z + a.w * w0.w;
        acc1 += a.x * w1.x + a.y * w1.y + a.z * w1.z + a.w * w1.w;
        if (cs + 16 < OUTN) {
            const float4 w2 = *(const float4*)&swt[cs + 16][k];
            acc2 += a.x * w2.x + a.y * w2.y + a.z * w2.z + a.w * w2.w;
        }
    }

    float* orow = outp + (size_t)(rowBase + r) * OUTN;
    orow[cs]     = acc0 + a0;
    orow[cs + 8] = acc1 + a1;
    if (cs + 16 < OUTN) orow[cs + 16] = acc2 + a2;
}

// ---------------------------------------------------------------------------
extern "C" void kernel_launch(void* const* d_in, const int* in_sizes, int n_in,
                              void* d_out, int out_size, void* d_ws, size_t ws_size,
                              hipStream_t stream)
{
    const float* emb     = (const float*)d_in[0];
    const float* W1      = (const float*)d_in[1];
    const float* b1      = (const float*)d_in[2];
    const float* W2      = (const float*)d_in[3];
    const float* b2      = (const float*)d_in[4];
    const int*   x       = (const int*)d_in[5];
    const int*   lengths = (const int*)d_in[6];

    float* out = (float*)d_out;

    const size_t embbN = (size_t)VOCAB * DIM;            // bf16 elems, 102.4 MB
    const size_t repbN = (size_t)BATCH * 2 * DIM;        // bf16 elems,   8.4 MB
    const size_t w1tN  = (size_t)HID * 2 * DIM;          // bf16 elems,   0.5 MB
    const size_t hN    = (size_t)BATCH * HID;            // fp32 elems,   4.2 MB
    const size_t needFast = (embbN + repbN + w1tN) * 2 + hN * 4 + 256;

    if (ws_size >= needFast) {
        unsigned short* embb = (unsigned short*)d_ws;
        unsigned short* repb = embb + embbN;
        unsigned short* w1t  = repb + repbN;
        float* h = (float*)(w1t + w1tN);

        k_cvt<<<2048, 256, 0, stream>>>(emb, embb);
        k_w1t<<<dim3(HID / 64, (2 * DIM) / 64), 256, 0, stream>>>(W1, w1t);
        k_reduce_bf<<<BATCH, 512, 0, stream>>>(embb, x, lengths, repb);
        k_gemm1<<<dim3(HID / 64, BATCH / 64), 256, 0, stream>>>(repb, w1t, b1, h);
        k_gemm2<<<BATCH / R3, 256, 0, stream>>>(h, W2, b2, out);
    } else {
        unsigned short* repb = (unsigned short*)d_ws;
        unsigned short* w1t  = repb + repbN;
        float* h = (float*)(w1t + w1tN);

        k_w1t<<<dim3(HID / 64, (2 * DIM) / 64), 256, 0, stream>>>(W1, w1t);
        k_reduce<<<BATCH, 128, 0, stream>>>(emb, x, lengths, repb);
        k_gemm1<<<dim3(HID / 64, BATCH / 64), 256, 0, stream>>>(repb, w1t, b1, h);
        k_gemm2<<<BATCH / R3, 256, 0, stream>>>(h, W2, b2, out);
    }
}